// Round 1
// baseline (435.200 us; speedup 1.0000x reference)
//
#include <hip/hip_runtime.h>

typedef unsigned short u16;
typedef __bf16 bf16x8 __attribute__((ext_vector_type(8)));
typedef float f32x4 __attribute__((ext_vector_type(4)));

#define M_ROWS 8232
#define SEQ 1029
#define NPREF 5
#define DIMN 1024
#define NH 16
#define HD 64

// address-space casts via integer round-trip (shared aperture is 4GB-aligned,
// so low 32 bits of a generic LDS pointer == LDS byte offset)
#define GP(p) ((__attribute__((address_space(1))) void*)(unsigned long long)(const void*)(p))
#define LP(p) ((__attribute__((address_space(3))) void*)(unsigned)(unsigned long long)(const void*)(p))

__device__ __forceinline__ u16 f2bf(float f) {
  unsigned u = __float_as_uint(f);
  u += 0x7fffu + ((u >> 16) & 1u);
  return (u16)(u >> 16);
}

// ---------------- x (fp32) -> bf16 ----------------
__global__ __launch_bounds__(256) void k_cvt_x(const float* __restrict__ x, u16* __restrict__ xb) {
  size_t i = ((size_t)blockIdx.x * 256 + threadIdx.x) * 4;
  float4 v = *reinterpret_cast<const float4*>(x + i);
  ushort4 o;
  o.x = f2bf(v.x); o.y = f2bf(v.y); o.z = f2bf(v.z); o.w = f2bf(v.w);
  *reinterpret_cast<ushort4*>(xb + i) = o;
}

// ---------------- W (fp32 [K][N]) -> WT (bf16 [N][K]) ----------------
__global__ __launch_bounds__(256) void k_wt(const float* __restrict__ W0, const float* __restrict__ W1,
                                            const float* __restrict__ W2, const float* __restrict__ W3,
                                            u16* __restrict__ T0, u16* __restrict__ T1,
                                            u16* __restrict__ T2, u16* __restrict__ T3) {
  const float* W; u16* T;
  switch (blockIdx.z) {
    case 0: W = W0; T = T0; break;
    case 1: W = W1; T = T1; break;
    case 2: W = W2; T = T2; break;
    default: W = W3; T = T3; break;
  }
  __shared__ float tile[32][33];
  int tx = threadIdx.x & 31, ty = threadIdx.x >> 5;
  int k0 = blockIdx.x * 32, n0 = blockIdx.y * 32;
#pragma unroll
  for (int j = 0; j < 4; ++j)
    tile[ty + j * 8][tx] = W[(size_t)(k0 + ty + j * 8) * DIMN + n0 + tx];
  __syncthreads();
#pragma unroll
  for (int j = 0; j < 4; ++j)
    T[(size_t)(n0 + ty + j * 8) * DIMN + k0 + tx] = f2bf(tile[tx][ty + j * 8]);
}

// ---------------- fused QKV projection GEMM ----------------
// C[m][n] = sum_k Xb[m][k] * W[k][n] ; W given transposed (WT[n][k], bf16)
// mode 0: Q (+bq, RoPE, *0.125) ; mode 1: K (RoPE) ; mode 2: V (+bv)
__global__ __launch_bounds__(256) void k_qkv(
    const u16* __restrict__ Xb,
    const u16* __restrict__ WqT, const u16* __restrict__ WkT, const u16* __restrict__ WvT,
    const float* __restrict__ bq, const float* __restrict__ bv,
    const float* __restrict__ rc, const float* __restrict__ rs,
    u16* __restrict__ Qg, u16* __restrict__ Kg, u16* __restrict__ Vg)
{
  int mode = blockIdx.z;
  const u16* WT = (mode == 0) ? WqT : (mode == 1) ? WkT : WvT;
  u16* dst = (mode == 0) ? Qg : (mode == 1) ? Kg : Vg;
  int m0 = blockIdx.x * 128, n0 = blockIdx.y * 128;

  __shared__ u16 Al[128 * 32];
  __shared__ u16 Bl[128 * 32];

  int t = threadIdx.x, lane = t & 63, wv = t >> 6;
  int fr = lane & 15, quad = lane >> 4;
  int wm = (wv >> 1) * 64, wn = (wv & 1) * 64;

  int srow = lane >> 2;
  int scol = (lane & 3) * 8;
  int ar0 = m0 + wv * 32 + srow; if (ar0 >= M_ROWS) ar0 = M_ROWS - 1;
  int ar1 = m0 + wv * 32 + 16 + srow; if (ar1 >= M_ROWS) ar1 = M_ROWS - 1;
  int br0 = n0 + wv * 32 + srow;
  int br1 = br0 + 16;
  const u16* agp0 = Xb + (size_t)ar0 * DIMN + scol;
  const u16* agp1 = Xb + (size_t)ar1 * DIMN + scol;
  const u16* bgp0 = WT + (size_t)br0 * DIMN + scol;
  const u16* bgp1 = WT + (size_t)br1 * DIMN + scol;
  u16* al0 = Al + wv * 1024;
  u16* al1 = Al + wv * 1024 + 512;
  u16* bl0 = Bl + wv * 1024;
  u16* bl1 = Bl + wv * 1024 + 512;

  f32x4 zero4 = {0.f, 0.f, 0.f, 0.f};
  f32x4 acc[4][4];
#pragma unroll
  for (int i = 0; i < 4; ++i)
#pragma unroll
    for (int j = 0; j < 4; ++j) acc[i][j] = zero4;

  for (int k0 = 0; k0 < DIMN; k0 += 32) {
    __syncthreads();
    __builtin_amdgcn_global_load_lds(GP(agp0 + k0), LP(al0), 16, 0, 0);
    __builtin_amdgcn_global_load_lds(GP(agp1 + k0), LP(al1), 16, 0, 0);
    __builtin_amdgcn_global_load_lds(GP(bgp0 + k0), LP(bl0), 16, 0, 0);
    __builtin_amdgcn_global_load_lds(GP(bgp1 + k0), LP(bl1), 16, 0, 0);
    __syncthreads();
    bf16x8 af[4], bfr[4];
#pragma unroll
    for (int i = 0; i < 4; ++i)
      af[i] = *reinterpret_cast<const bf16x8*>(&Al[(wm + i * 16 + fr) * 32 + quad * 8]);
#pragma unroll
    for (int j = 0; j < 4; ++j)
      bfr[j] = *reinterpret_cast<const bf16x8*>(&Bl[(wn + j * 16 + fr) * 32 + quad * 8]);
#pragma unroll
    for (int i = 0; i < 4; ++i)
#pragma unroll
      for (int j = 0; j < 4; ++j)
        acc[i][j] = __builtin_amdgcn_mfma_f32_16x16x32_bf16(af[i], bfr[j], acc[i][j], 0, 0, 0);
  }

  int h = (n0 + wn) >> 6;  // wave spans exactly one 64-wide head
#pragma unroll
  for (int i = 0; i < 4; ++i) {
    int rowbase = m0 + wm + i * 16 + quad * 4;
#pragma unroll
    for (int r = 0; r < 4; ++r) {
      int row = rowbase + r;
      if (row >= M_ROWS) continue;
      int b = row / SEQ;
      int s = row - b * SEQ;
#pragma unroll
      for (int j = 0; j < 4; ++j) {
        int d = j * 16 + fr;
        float v = acc[i][j][r];
        float outv;
        if (mode == 2) {
          outv = v + bv[n0 + wn + d];
        } else {
          float vb = v;
          int jp = j ^ 2;
          float pv = acc[i][jp][r];
          if (mode == 0) {
            vb += bq[n0 + wn + d];
            pv += bq[n0 + wn + (jp * 16 + fr)];
          }
          if (s >= NPREF) {
            int p = s - NPREF;
            float c = rc[p * HD + d];
            float sn = rs[p * HD + d];
            float rot = (d < 32) ? -pv : pv;
            outv = vb * c + rot * sn;
          } else {
            outv = vb;
          }
          if (mode == 0) outv *= 0.125f;
        }
        dst[((size_t)(b * NH + h) * SEQ + s) * HD + d] = f2bf(outv);
      }
    }
  }
}

// ---------------- flash attention ----------------
// grid: x = 17 q-tiles of 64, y = 128 (b*16+h). block 256 (4 waves x 16 q-rows).
__global__ __launch_bounds__(256) void k_attn(
    const u16* __restrict__ Qg, const u16* __restrict__ Kg, const u16* __restrict__ Vg,
    u16* __restrict__ AO)
{
  int qt = blockIdx.x;
  int bh = blockIdx.y;
  int b = bh >> 4, h = bh & 15;
  int q0 = qt * 64;
  const size_t base = (size_t)bh * SEQ * HD;

  __shared__ u16 Qs[64 * 72];
  __shared__ u16 Ks[64 * 72];
  __shared__ u16 Vt[64 * 72];
  __shared__ u16 Ps[4][16 * 72];

  int t = threadIdx.x, lane = t & 63, wv = t >> 6;
  int fr = lane & 15, quad = lane >> 4;

  // stage Q tile once (rows clamped; garbage rows never written out)
  {
    int i = t >> 2;
    int srow = q0 + i; if (srow >= SEQ) srow = SEQ - 1;
    const u16* src = Qg + base + (size_t)srow * HD;
    int c0 = (t & 3) * 16;
    *reinterpret_cast<uint4*>(&Qs[i * 72 + c0]) = *reinterpret_cast<const uint4*>(src + c0);
    *reinterpret_cast<uint4*>(&Qs[i * 72 + c0 + 8]) = *reinterpret_cast<const uint4*>(src + c0 + 8);
  }

  float m_st[4], l_st[4];
  f32x4 zero4 = {0.f, 0.f, 0.f, 0.f};
  f32x4 o_acc[4];
#pragma unroll
  for (int r = 0; r < 4; ++r) { m_st[r] = -1e30f; l_st[r] = 0.f; }
#pragma unroll
  for (int di = 0; di < 4; ++di) o_acc[di] = zero4;

  for (int kt = 0; kt < 17; ++kt) {
    int k0 = kt * 64;
    __syncthreads();
    // stage K tile [s][d]
    {
      int i = t >> 2;
      int srow = k0 + i; if (srow >= SEQ) srow = SEQ - 1;
      const u16* src = Kg + base + (size_t)srow * HD;
      int c0 = (t & 3) * 16;
      *reinterpret_cast<uint4*>(&Ks[i * 72 + c0]) = *reinterpret_cast<const uint4*>(src + c0);
      *reinterpret_cast<uint4*>(&Ks[i * 72 + c0 + 8]) = *reinterpret_cast<const uint4*>(src + c0 + 8);
    }
    // stage V transposed: Vt[d][s], packed pair-of-s dword writes (conflict-free)
    {
      int s0 = (t & 31) * 2;
      int doff = (t >> 5) * 8;
      int r0 = k0 + s0;     if (r0 >= SEQ) r0 = SEQ - 1;
      int r1 = k0 + s0 + 1; if (r1 >= SEQ) r1 = SEQ - 1;
      const u16* v0p = Vg + base + (size_t)r0 * HD + doff;
      const u16* v1p = Vg + base + (size_t)r1 * HD + doff;
      u16 v0[8], v1[8];
      *reinterpret_cast<uint4*>(v0) = *reinterpret_cast<const uint4*>(v0p);
      *reinterpret_cast<uint4*>(v1) = *reinterpret_cast<const uint4*>(v1p);
#pragma unroll
      for (int j = 0; j < 8; ++j) {
        unsigned pk = (unsigned)v0[j] | ((unsigned)v1[j] << 16);
        *reinterpret_cast<unsigned*>(&Vt[(doff + j) * 72 + s0]) = pk;
      }
    }
    __syncthreads();

    // S = Q K^T (this wave: 16 q-rows x 64 k-cols)
    f32x4 sc[4];
#pragma unroll
    for (int ni = 0; ni < 4; ++ni) sc[ni] = zero4;
#pragma unroll
    for (int st = 0; st < 2; ++st) {
      bf16x8 qf = *reinterpret_cast<const bf16x8*>(&Qs[(wv * 16 + fr) * 72 + st * 32 + quad * 8]);
#pragma unroll
      for (int ni = 0; ni < 4; ++ni) {
        bf16x8 kf = *reinterpret_cast<const bf16x8*>(&Ks[(ni * 16 + fr) * 72 + st * 32 + quad * 8]);
        sc[ni] = __builtin_amdgcn_mfma_f32_16x16x32_bf16(qf, kf, sc[ni], 0, 0, 0);
      }
    }

    // online softmax (row = quad*4+r, cols spread over the 16 lanes of the quad-group)
    float pj[4][4], alpha[4];
#pragma unroll
    for (int r = 0; r < 4; ++r) {
      float rm = -1e30f;
#pragma unroll
      for (int ni = 0; ni < 4; ++ni) {
        int skg = k0 + ni * 16 + fr;
        float v = (skg < SEQ) ? sc[ni][r] : -1e30f;
        pj[ni][r] = v;
        rm = fmaxf(rm, v);
      }
      rm = fmaxf(rm, __shfl_xor(rm, 1));
      rm = fmaxf(rm, __shfl_xor(rm, 2));
      rm = fmaxf(rm, __shfl_xor(rm, 4));
      rm = fmaxf(rm, __shfl_xor(rm, 8));
      float mn = fmaxf(m_st[r], rm);
      float al = __expf(m_st[r] - mn);
      float rsum = 0.f;
#pragma unroll
      for (int ni = 0; ni < 4; ++ni) {
        float pe = __expf(pj[ni][r] - mn);
        pj[ni][r] = pe;
        rsum += pe;
      }
      rsum += __shfl_xor(rsum, 1);
      rsum += __shfl_xor(rsum, 2);
      rsum += __shfl_xor(rsum, 4);
      rsum += __shfl_xor(rsum, 8);
      l_st[r] = l_st[r] * al + rsum;
      m_st[r] = mn;
      alpha[r] = al;
    }
#pragma unroll
    for (int di = 0; di < 4; ++di)
#pragma unroll
      for (int r = 0; r < 4; ++r) o_acc[di][r] *= alpha[r];

    // P -> LDS (C-layout -> A-layout round trip, wave-private region)
#pragma unroll
    for (int ni = 0; ni < 4; ++ni)
#pragma unroll
      for (int r = 0; r < 4; ++r)
        Ps[wv][(quad * 4 + r) * 72 + ni * 16 + fr] = f2bf(pj[ni][r]);
    __syncthreads();

    // O += P V
#pragma unroll
    for (int st = 0; st < 2; ++st) {
      bf16x8 pf = *reinterpret_cast<const bf16x8*>(&Ps[wv][fr * 72 + st * 32 + quad * 8]);
#pragma unroll
      for (int di = 0; di < 4; ++di) {
        bf16x8 vf = *reinterpret_cast<const bf16x8*>(&Vt[(di * 16 + fr) * 72 + st * 32 + quad * 8]);
        o_acc[di] = __builtin_amdgcn_mfma_f32_16x16x32_bf16(pf, vf, o_acc[di], 0, 0, 0);
      }
    }
  }

  // epilogue: AO[b][s][h*64+d] bf16 (feeds final GEMM as A matrix)
#pragma unroll
  for (int r = 0; r < 4; ++r) {
    int srow = q0 + wv * 16 + quad * 4 + r;
    if (srow >= SEQ) continue;
    float inv = 1.f / l_st[r];
#pragma unroll
    for (int di = 0; di < 4; ++di) {
      float v = o_acc[di][r] * inv;
      AO[((size_t)b * SEQ + srow) * DIMN + h * HD + di * 16 + fr] = f2bf(v);
    }
  }
}

// ---------------- output GEMM: Out = AO @ Wo + bo (fp32 out) ----------------
__global__ __launch_bounds__(256) void k_out(
    const u16* __restrict__ Ab, const u16* __restrict__ WoT,
    const float* __restrict__ bo, float* __restrict__ Out)
{
  int m0 = blockIdx.x * 128, n0 = blockIdx.y * 128;
  __shared__ u16 Al[128 * 32];
  __shared__ u16 Bl[128 * 32];

  int t = threadIdx.x, lane = t & 63, wv = t >> 6;
  int fr = lane & 15, quad = lane >> 4;
  int wm = (wv >> 1) * 64, wn = (wv & 1) * 64;

  int srow = lane >> 2;
  int scol = (lane & 3) * 8;
  int ar0 = m0 + wv * 32 + srow; if (ar0 >= M_ROWS) ar0 = M_ROWS - 1;
  int ar1 = m0 + wv * 32 + 16 + srow; if (ar1 >= M_ROWS) ar1 = M_ROWS - 1;
  int br0 = n0 + wv * 32 + srow;
  int br1 = br0 + 16;
  const u16* agp0 = Ab + (size_t)ar0 * DIMN + scol;
  const u16* agp1 = Ab + (size_t)ar1 * DIMN + scol;
  const u16* bgp0 = WoT + (size_t)br0 * DIMN + scol;
  const u16* bgp1 = WoT + (size_t)br1 * DIMN + scol;
  u16* al0 = Al + wv * 1024;
  u16* al1 = Al + wv * 1024 + 512;
  u16* bl0 = Bl + wv * 1024;
  u16* bl1 = Bl + wv * 1024 + 512;

  f32x4 zero4 = {0.f, 0.f, 0.f, 0.f};
  f32x4 acc[4][4];
#pragma unroll
  for (int i = 0; i < 4; ++i)
#pragma unroll
    for (int j = 0; j < 4; ++j) acc[i][j] = zero4;

  for (int k0 = 0; k0 < DIMN; k0 += 32) {
    __syncthreads();
    __builtin_amdgcn_global_load_lds(GP(agp0 + k0), LP(al0), 16, 0, 0);
    __builtin_amdgcn_global_load_lds(GP(agp1 + k0), LP(al1), 16, 0, 0);
    __builtin_amdgcn_global_load_lds(GP(bgp0 + k0), LP(bl0), 16, 0, 0);
    __builtin_amdgcn_global_load_lds(GP(bgp1 + k0), LP(bl1), 16, 0, 0);
    __syncthreads();
    bf16x8 af[4], bfr[4];
#pragma unroll
    for (int i = 0; i < 4; ++i)
      af[i] = *reinterpret_cast<const bf16x8*>(&Al[(wm + i * 16 + fr) * 32 + quad * 8]);
#pragma unroll
    for (int j = 0; j < 4; ++j)
      bfr[j] = *reinterpret_cast<const bf16x8*>(&Bl[(wn + j * 16 + fr) * 32 + quad * 8]);
#pragma unroll
    for (int i = 0; i < 4; ++i)
#pragma unroll
      for (int j = 0; j < 4; ++j)
        acc[i][j] = __builtin_amdgcn_mfma_f32_16x16x32_bf16(af[i], bfr[j], acc[i][j], 0, 0, 0);
  }

#pragma unroll
  for (int i = 0; i < 4; ++i) {
    int rowbase = m0 + wm + i * 16 + quad * 4;
#pragma unroll
    for (int r = 0; r < 4; ++r) {
      int row = rowbase + r;
      if (row >= M_ROWS) continue;
#pragma unroll
      for (int j = 0; j < 4; ++j) {
        int col = n0 + wn + j * 16 + fr;
        Out[(size_t)row * DIMN + col] = acc[i][j][r] + bo[col];
      }
    }
  }
}

extern "C" void kernel_launch(void* const* d_in, const int* in_sizes, int n_in,
                              void* d_out, int out_size, void* d_ws, size_t ws_size,
                              hipStream_t stream)
{
  const float* x  = (const float*)d_in[0];
  const float* rc = (const float*)d_in[1];
  const float* rs = (const float*)d_in[2];
  const float* Wq = (const float*)d_in[3];
  const float* bq = (const float*)d_in[4];
  const float* Wk = (const float*)d_in[5];
  const float* Wv = (const float*)d_in[6];
  const float* bv = (const float*)d_in[7];
  const float* Wo = (const float*)d_in[8];
  const float* bo = (const float*)d_in[9];
  float* Out = (float*)d_out;

  u16* p = (u16*)d_ws;
  u16* Xb  = p; p += (size_t)M_ROWS * DIMN;
  u16* WqT = p; p += (size_t)DIMN * DIMN;
  u16* WkT = p; p += (size_t)DIMN * DIMN;
  u16* WvT = p; p += (size_t)DIMN * DIMN;
  u16* WoT = p; p += (size_t)DIMN * DIMN;
  u16* Qg  = p; p += (size_t)M_ROWS * DIMN;
  u16* Kg  = p; p += (size_t)M_ROWS * DIMN;
  u16* Vg  = p; p += (size_t)M_ROWS * DIMN;
  u16* AO  = p; p += (size_t)M_ROWS * DIMN;

  k_cvt_x<<<M_ROWS, 256, 0, stream>>>(x, Xb);  // 8232*1024 elems / (256*4) = 8232 blocks
  dim3 gt(32, 32, 4);
  k_wt<<<gt, 256, 0, stream>>>(Wq, Wk, Wv, Wo, WqT, WkT, WvT, WoT);
  dim3 g1(65, 8, 3);
  k_qkv<<<g1, 256, 0, stream>>>(Xb, WqT, WkT, WvT, bq, bv, rc, rs, Qg, Kg, Vg);
  dim3 g2(17, 128);
  k_attn<<<g2, 256, 0, stream>>>(Qg, Kg, Vg, AO);
  dim3 g3(65, 8);
  k_out<<<g3, 256, 0, stream>>>(AO, WoT, bo, Out);
}

// Round 2
// 375.700 us; speedup vs baseline: 1.1584x; 1.1584x over previous
//
#include <hip/hip_runtime.h>

typedef unsigned short u16;
typedef __bf16 bf16x8 __attribute__((ext_vector_type(8)));
typedef unsigned short u16x8 __attribute__((ext_vector_type(8)));
typedef float f32x4 __attribute__((ext_vector_type(4)));

#define M_ROWS 8232
#define SEQ 1029
#define NPREF 5
#define DIMN 1024
#define NH 16
#define HD 64

#define GP(p) ((__attribute__((address_space(1))) void*)(unsigned long long)(const void*)(p))
#define LP(p) ((__attribute__((address_space(3))) void*)(unsigned)(unsigned long long)(const void*)(p))

__device__ __forceinline__ u16 f2bf(float f) {
  unsigned u = __float_as_uint(f);
  u += 0x7fffu + ((u >> 16) & 1u);
  return (u16)(u >> 16);
}

// pack two fp32 -> bf16x2 dword (lo in low half) with RNE, via v_perm
__device__ __forceinline__ unsigned pk2bf(float lo, float hi) {
  unsigned ul = __float_as_uint(lo);
  unsigned uh = __float_as_uint(hi);
  ul += 0x7fffu + ((ul >> 16) & 1u);
  uh += 0x7fffu + ((uh >> 16) & 1u);
  return __builtin_amdgcn_perm(uh, ul, 0x07060302u);  // bytes: uh[3],uh[2],ul[3],ul[2]
}

// ---------------- x (fp32) -> bf16 ----------------
__global__ __launch_bounds__(256) void k_cvt_x(const float* __restrict__ x, u16* __restrict__ xb) {
  size_t i = ((size_t)blockIdx.x * 256 + threadIdx.x) * 4;
  float4 v = *reinterpret_cast<const float4*>(x + i);
  ushort4 o;
  o.x = f2bf(v.x); o.y = f2bf(v.y); o.z = f2bf(v.z); o.w = f2bf(v.w);
  *reinterpret_cast<ushort4*>(xb + i) = o;
}

// ---------------- W (fp32 [K][N]) -> WT (bf16 [N][K]) ----------------
__global__ __launch_bounds__(256) void k_wt(const float* __restrict__ W0, const float* __restrict__ W1,
                                            const float* __restrict__ W2, const float* __restrict__ W3,
                                            u16* __restrict__ T0, u16* __restrict__ T1,
                                            u16* __restrict__ T2, u16* __restrict__ T3) {
  const float* W; u16* T;
  switch (blockIdx.z) {
    case 0: W = W0; T = T0; break;
    case 1: W = W1; T = T1; break;
    case 2: W = W2; T = T2; break;
    default: W = W3; T = T3; break;
  }
  __shared__ float tile[32][33];
  int tx = threadIdx.x & 31, ty = threadIdx.x >> 5;
  int k0 = blockIdx.x * 32, n0 = blockIdx.y * 32;
#pragma unroll
  for (int j = 0; j < 4; ++j)
    tile[ty + j * 8][tx] = W[(size_t)(k0 + ty + j * 8) * DIMN + n0 + tx];
  __syncthreads();
#pragma unroll
  for (int j = 0; j < 4; ++j)
    T[(size_t)(n0 + ty + j * 8) * DIMN + k0 + tx] = f2bf(tile[tx][ty + j * 8]);
}

// ---------------- fused QKV projection GEMM ----------------
__global__ __launch_bounds__(256) void k_qkv(
    const u16* __restrict__ Xb,
    const u16* __restrict__ WqT, const u16* __restrict__ WkT, const u16* __restrict__ WvT,
    const float* __restrict__ bq, const float* __restrict__ bv,
    const float* __restrict__ rc, const float* __restrict__ rs,
    u16* __restrict__ Qg, u16* __restrict__ Kg, u16* __restrict__ Vg)
{
  int mode = blockIdx.z;
  const u16* WT = (mode == 0) ? WqT : (mode == 1) ? WkT : WvT;
  u16* dst = (mode == 0) ? Qg : (mode == 1) ? Kg : Vg;
  int m0 = blockIdx.x * 128, n0 = blockIdx.y * 128;

  __shared__ u16 Al[128 * 32];
  __shared__ u16 Bl[128 * 32];

  int t = threadIdx.x, lane = t & 63, wv = t >> 6;
  int fr = lane & 15, quad = lane >> 4;
  int wm = (wv >> 1) * 64, wn = (wv & 1) * 64;

  int srow = lane >> 2;
  int scol = (lane & 3) * 8;
  int ar0 = m0 + wv * 32 + srow; if (ar0 >= M_ROWS) ar0 = M_ROWS - 1;
  int ar1 = m0 + wv * 32 + 16 + srow; if (ar1 >= M_ROWS) ar1 = M_ROWS - 1;
  int br0 = n0 + wv * 32 + srow;
  int br1 = br0 + 16;
  const u16* agp0 = Xb + (size_t)ar0 * DIMN + scol;
  const u16* agp1 = Xb + (size_t)ar1 * DIMN + scol;
  const u16* bgp0 = WT + (size_t)br0 * DIMN + scol;
  const u16* bgp1 = WT + (size_t)br1 * DIMN + scol;
  u16* al0 = Al + wv * 1024;
  u16* al1 = Al + wv * 1024 + 512;
  u16* bl0 = Bl + wv * 1024;
  u16* bl1 = Bl + wv * 1024 + 512;

  f32x4 zero4 = {0.f, 0.f, 0.f, 0.f};
  f32x4 acc[4][4];
#pragma unroll
  for (int i = 0; i < 4; ++i)
#pragma unroll
    for (int j = 0; j < 4; ++j) acc[i][j] = zero4;

  for (int k0 = 0; k0 < DIMN; k0 += 32) {
    __syncthreads();
    __builtin_amdgcn_global_load_lds(GP(agp0 + k0), LP(al0), 16, 0, 0);
    __builtin_amdgcn_global_load_lds(GP(agp1 + k0), LP(al1), 16, 0, 0);
    __builtin_amdgcn_global_load_lds(GP(bgp0 + k0), LP(bl0), 16, 0, 0);
    __builtin_amdgcn_global_load_lds(GP(bgp1 + k0), LP(bl1), 16, 0, 0);
    __syncthreads();
    bf16x8 af[4], bfr[4];
#pragma unroll
    for (int i = 0; i < 4; ++i)
      af[i] = *reinterpret_cast<const bf16x8*>(&Al[(wm + i * 16 + fr) * 32 + quad * 8]);
#pragma unroll
    for (int j = 0; j < 4; ++j)
      bfr[j] = *reinterpret_cast<const bf16x8*>(&Bl[(wn + j * 16 + fr) * 32 + quad * 8]);
#pragma unroll
    for (int i = 0; i < 4; ++i)
#pragma unroll
      for (int j = 0; j < 4; ++j)
        acc[i][j] = __builtin_amdgcn_mfma_f32_16x16x32_bf16(af[i], bfr[j], acc[i][j], 0, 0, 0);
  }

  int h = (n0 + wn) >> 6;
#pragma unroll
  for (int i = 0; i < 4; ++i) {
    int rowbase = m0 + wm + i * 16 + quad * 4;
#pragma unroll
    for (int r = 0; r < 4; ++r) {
      int row = rowbase + r;
      if (row >= M_ROWS) continue;
      int b = row / SEQ;
      int s = row - b * SEQ;
#pragma unroll
      for (int j = 0; j < 4; ++j) {
        int d = j * 16 + fr;
        float v = acc[i][j][r];
        float outv;
        if (mode == 2) {
          outv = v + bv[n0 + wn + d];
        } else {
          float vb = v;
          int jp = j ^ 2;
          float pv = acc[i][jp][r];
          if (mode == 0) {
            vb += bq[n0 + wn + d];
            pv += bq[n0 + wn + (jp * 16 + fr)];
          }
          if (s >= NPREF) {
            int p = s - NPREF;
            float c = rc[p * HD + d];
            float sn = rs[p * HD + d];
            float rot = (d < 32) ? -pv : pv;
            outv = vb * c + rot * sn;
          } else {
            outv = vb;
          }
          if (mode == 0) outv *= 0.125f;
        }
        dst[((size_t)(b * NH + h) * SEQ + s) * HD + d] = f2bf(outv);
      }
    }
  }
}

// ---------------- flash attention, S^T layout, fixed-M softmax ----------------
// grid: x = 9 q-tiles of 128, y = 128 (b*16+h). block 256 (4 waves x 32 q-rows).
__global__ __launch_bounds__(256) void k_attn(
    const u16* __restrict__ Qg, const u16* __restrict__ Kg, const u16* __restrict__ Vg,
    u16* __restrict__ AO)
{
  int q0 = blockIdx.x * 128;
  int bh = blockIdx.y;
  int b = bh >> 4, h = bh & 15;
  const size_t base = (size_t)bh * SEQ * HD;

  __shared__ u16 Ks[64 * 72];      // K tile [s][d]
  __shared__ u16 Vt[64 * 72];      // V tile transposed [d][s]
  __shared__ u16 Ps[4][32 * 72];   // per-wave P [qrow 0..31][kcol 0..63]

  int t = threadIdx.x, lane = t & 63, wv = t >> 6;
  int fr = lane & 15, quad = lane >> 4;

  // Q B-fragments straight from global into registers (once).
  // B-frag: lane holds B[n=fr][k=quad*8+j], k = st*32 + quad*8 + j
  bf16x8 qf[2][2];
#pragma unroll
  for (int qt = 0; qt < 2; ++qt) {
#pragma unroll
    for (int st = 0; st < 2; ++st) {
      int row = q0 + wv * 32 + qt * 16 + fr;
      if (row >= SEQ) row = SEQ - 1;
      qf[qt][st] = *reinterpret_cast<const bf16x8*>(Qg + base + (size_t)row * HD + st * 32 + quad * 8);
    }
  }

  // all-ones B-fragment for the row-sum accumulator tile
  u16x8 one16 = {0x3F80, 0x3F80, 0x3F80, 0x3F80, 0x3F80, 0x3F80, 0x3F80, 0x3F80};
  bf16x8 vone = __builtin_bit_cast(bf16x8, one16);

  f32x4 zero4 = {0.f, 0.f, 0.f, 0.f};
  f32x4 o[2][5];  // [qt][di 0..3 = output dims, 4 = row-sum l]
#pragma unroll
  for (int qt = 0; qt < 2; ++qt)
#pragma unroll
    for (int di = 0; di < 5; ++di) o[qt][di] = zero4;

  for (int kt = 0; kt < 17; ++kt) {
    int k0 = kt * 64;
    __syncthreads();
    // stage K tile [s][d]
    {
      int i = t >> 2;
      int srow = k0 + i; if (srow >= SEQ) srow = SEQ - 1;
      const u16* src = Kg + base + (size_t)srow * HD;
      int c0 = (t & 3) * 16;
      *reinterpret_cast<uint4*>(&Ks[i * 72 + c0]) = *reinterpret_cast<const uint4*>(src + c0);
      *reinterpret_cast<uint4*>(&Ks[i * 72 + c0 + 8]) = *reinterpret_cast<const uint4*>(src + c0 + 8);
    }
    // stage V transposed: Vt[d][s]
    {
      int s0 = (t & 31) * 2;
      int doff = (t >> 5) * 8;
      int r0 = k0 + s0;     if (r0 >= SEQ) r0 = SEQ - 1;
      int r1 = k0 + s0 + 1; if (r1 >= SEQ) r1 = SEQ - 1;
      const u16* v0p = Vg + base + (size_t)r0 * HD + doff;
      const u16* v1p = Vg + base + (size_t)r1 * HD + doff;
      u16 v0[8], v1[8];
      *reinterpret_cast<uint4*>(v0) = *reinterpret_cast<const uint4*>(v0p);
      *reinterpret_cast<uint4*>(v1) = *reinterpret_cast<const uint4*>(v1p);
#pragma unroll
      for (int j = 0; j < 8; ++j) {
        unsigned pk = (unsigned)v0[j] | ((unsigned)v1[j] << 16);
        *reinterpret_cast<unsigned*>(&Vt[(doff + j) * 72 + s0]) = pk;
      }
    }
    __syncthreads();

    // S^T = K Q^T : lane holds (kcol = mi*16 + quad*4 + r, qrow = qt*16 + fr)
    f32x4 sc[4][2];
#pragma unroll
    for (int mi = 0; mi < 4; ++mi)
#pragma unroll
      for (int qt = 0; qt < 2; ++qt) sc[mi][qt] = zero4;
#pragma unroll
    for (int st = 0; st < 2; ++st) {
#pragma unroll
      for (int mi = 0; mi < 4; ++mi) {
        bf16x8 kf = *reinterpret_cast<const bf16x8*>(&Ks[(mi * 16 + fr) * 72 + st * 32 + quad * 8]);
#pragma unroll
        for (int qt = 0; qt < 2; ++qt)
          sc[mi][qt] = __builtin_amdgcn_mfma_f32_16x16x32_bf16(kf, qf[qt][st], sc[mi][qt], 0, 0, 0);
      }
    }

    // fixed-M softmax: p = exp(s - 16); mask padding k only in the last tile
    bool last = (kt == 16);
#pragma unroll
    for (int qt = 0; qt < 2; ++qt) {
#pragma unroll
      for (int mi = 0; mi < 4; ++mi) {
        float p0, p1, p2, p3;
        {
          float s0v = sc[mi][qt][0], s1v = sc[mi][qt][1], s2v = sc[mi][qt][2], s3v = sc[mi][qt][3];
          if (last) {
            int kc = mi * 16 + quad * 4;  // local kcol of r=0; global = 1024 + kc
            if (kc + 0 >= NPREF) s0v = -1e30f;
            if (kc + 1 >= NPREF) s1v = -1e30f;
            if (kc + 2 >= NPREF) s2v = -1e30f;
            if (kc + 3 >= NPREF) s3v = -1e30f;
          }
          p0 = __expf(s0v - 16.0f);
          p1 = __expf(s1v - 16.0f);
          p2 = __expf(s2v - 16.0f);
          p3 = __expf(s3v - 16.0f);
        }
        unsigned d0 = pk2bf(p0, p1);
        unsigned d1 = pk2bf(p2, p3);
        uint2 w; w.x = d0; w.y = d1;
        *reinterpret_cast<uint2*>(&Ps[wv][(qt * 16 + fr) * 72 + mi * 16 + quad * 4]) = w;
      }
    }
    // no barrier: Ps is wave-private, same-wave LDS ops are ordered

    // O += P V  (A = P from LDS, B = V^T from LDS; extra ones-tile accumulates l)
#pragma unroll
    for (int st = 0; st < 2; ++st) {
      bf16x8 pf[2];
#pragma unroll
      for (int qt = 0; qt < 2; ++qt)
        pf[qt] = *reinterpret_cast<const bf16x8*>(&Ps[wv][(qt * 16 + fr) * 72 + st * 32 + quad * 8]);
#pragma unroll
      for (int di = 0; di < 4; ++di) {
        bf16x8 vf = *reinterpret_cast<const bf16x8*>(&Vt[(di * 16 + fr) * 72 + st * 32 + quad * 8]);
#pragma unroll
        for (int qt = 0; qt < 2; ++qt)
          o[qt][di] = __builtin_amdgcn_mfma_f32_16x16x32_bf16(pf[qt], vf, o[qt][di], 0, 0, 0);
      }
#pragma unroll
      for (int qt = 0; qt < 2; ++qt)
        o[qt][4] = __builtin_amdgcn_mfma_f32_16x16x32_bf16(pf[qt], vone, o[qt][4], 0, 0, 0);
    }
  }

  // epilogue: lane holds (q = qt*16 + quad*4 + r, d = di*16 + fr); l in o[qt][4][r]
#pragma unroll
  for (int qt = 0; qt < 2; ++qt) {
#pragma unroll
    for (int r = 0; r < 4; ++r) {
      int srow = q0 + wv * 32 + qt * 16 + quad * 4 + r;
      if (srow >= SEQ) continue;
      float inv = 1.f / o[qt][4][r];
#pragma unroll
      for (int di = 0; di < 4; ++di) {
        float v = o[qt][di][r] * inv;
        AO[((size_t)b * SEQ + srow) * DIMN + h * HD + di * 16 + fr] = f2bf(v);
      }
    }
  }
}

// ---------------- output GEMM: Out = AO @ Wo + bo (fp32 out) ----------------
__global__ __launch_bounds__(256) void k_out(
    const u16* __restrict__ Ab, const u16* __restrict__ WoT,
    const float* __restrict__ bo, float* __restrict__ Out)
{
  int m0 = blockIdx.x * 128, n0 = blockIdx.y * 128;
  __shared__ u16 Al[128 * 32];
  __shared__ u16 Bl[128 * 32];

  int t = threadIdx.x, lane = t & 63, wv = t >> 6;
  int fr = lane & 15, quad = lane >> 4;
  int wm = (wv >> 1) * 64, wn = (wv & 1) * 64;

  int srow = lane >> 2;
  int scol = (lane & 3) * 8;
  int ar0 = m0 + wv * 32 + srow; if (ar0 >= M_ROWS) ar0 = M_ROWS - 1;
  int ar1 = m0 + wv * 32 + 16 + srow; if (ar1 >= M_ROWS) ar1 = M_ROWS - 1;
  int br0 = n0 + wv * 32 + srow;
  int br1 = br0 + 16;
  const u16* agp0 = Ab + (size_t)ar0 * DIMN + scol;
  const u16* agp1 = Ab + (size_t)ar1 * DIMN + scol;
  const u16* bgp0 = WoT + (size_t)br0 * DIMN + scol;
  const u16* bgp1 = WoT + (size_t)br1 * DIMN + scol;
  u16* al0 = Al + wv * 1024;
  u16* al1 = Al + wv * 1024 + 512;
  u16* bl0 = Bl + wv * 1024;
  u16* bl1 = Bl + wv * 1024 + 512;

  f32x4 zero4 = {0.f, 0.f, 0.f, 0.f};
  f32x4 acc[4][4];
#pragma unroll
  for (int i = 0; i < 4; ++i)
#pragma unroll
    for (int j = 0; j < 4; ++j) acc[i][j] = zero4;

  for (int k0 = 0; k0 < DIMN; k0 += 32) {
    __syncthreads();
    __builtin_amdgcn_global_load_lds(GP(agp0 + k0), LP(al0), 16, 0, 0);
    __builtin_amdgcn_global_load_lds(GP(agp1 + k0), LP(al1), 16, 0, 0);
    __builtin_amdgcn_global_load_lds(GP(bgp0 + k0), LP(bl0), 16, 0, 0);
    __builtin_amdgcn_global_load_lds(GP(bgp1 + k0), LP(bl1), 16, 0, 0);
    __syncthreads();
    bf16x8 af[4], bfr[4];
#pragma unroll
    for (int i = 0; i < 4; ++i)
      af[i] = *reinterpret_cast<const bf16x8*>(&Al[(wm + i * 16 + fr) * 32 + quad * 8]);
#pragma unroll
    for (int j = 0; j < 4; ++j)
      bfr[j] = *reinterpret_cast<const bf16x8*>(&Bl[(wn + j * 16 + fr) * 32 + quad * 8]);
#pragma unroll
    for (int i = 0; i < 4; ++i)
#pragma unroll
      for (int j = 0; j < 4; ++j)
        acc[i][j] = __builtin_amdgcn_mfma_f32_16x16x32_bf16(af[i], bfr[j], acc[i][j], 0, 0, 0);
  }

#pragma unroll
  for (int i = 0; i < 4; ++i) {
    int rowbase = m0 + wm + i * 16 + quad * 4;
#pragma unroll
    for (int r = 0; r < 4; ++r) {
      int row = rowbase + r;
      if (row >= M_ROWS) continue;
#pragma unroll
      for (int j = 0; j < 4; ++j) {
        int col = n0 + wn + j * 16 + fr;
        Out[(size_t)row * DIMN + col] = acc[i][j][r] + bo[col];
      }
    }
  }
}

extern "C" void kernel_launch(void* const* d_in, const int* in_sizes, int n_in,
                              void* d_out, int out_size, void* d_ws, size_t ws_size,
                              hipStream_t stream)
{
  const float* x  = (const float*)d_in[0];
  const float* rc = (const float*)d_in[1];
  const float* rs = (const float*)d_in[2];
  const float* Wq = (const float*)d_in[3];
  const float* bq = (const float*)d_in[4];
  const float* Wk = (const float*)d_in[5];
  const float* Wv = (const float*)d_in[6];
  const float* bv = (const float*)d_in[7];
  const float* Wo = (const float*)d_in[8];
  const float* bo = (const float*)d_in[9];
  float* Out = (float*)d_out;

  u16* p = (u16*)d_ws;
  u16* Xb  = p; p += (size_t)M_ROWS * DIMN;
  u16* WqT = p; p += (size_t)DIMN * DIMN;
  u16* WkT = p; p += (size_t)DIMN * DIMN;
  u16* WvT = p; p += (size_t)DIMN * DIMN;
  u16* WoT = p; p += (size_t)DIMN * DIMN;
  u16* Qg  = p; p += (size_t)M_ROWS * DIMN;
  u16* Kg  = p; p += (size_t)M_ROWS * DIMN;
  u16* Vg  = p; p += (size_t)M_ROWS * DIMN;
  u16* AO  = p; p += (size_t)M_ROWS * DIMN;

  k_cvt_x<<<M_ROWS, 256, 0, stream>>>(x, Xb);
  dim3 gt(32, 32, 4);
  k_wt<<<gt, 256, 0, stream>>>(Wq, Wk, Wv, Wo, WqT, WkT, WvT, WoT);
  dim3 g1(65, 8, 3);
  k_qkv<<<g1, 256, 0, stream>>>(Xb, WqT, WkT, WvT, bq, bv, rc, rs, Qg, Kg, Vg);
  dim3 g2(9, 128);
  k_attn<<<g2, 256, 0, stream>>>(Qg, Kg, Vg, AO);
  dim3 g3(65, 8);
  k_out<<<g3, 256, 0, stream>>>(AO, WoT, bo, Out);
}

// Round 3
// 362.139 us; speedup vs baseline: 1.2017x; 1.0374x over previous
//
#include <hip/hip_runtime.h>

typedef unsigned short u16;
typedef __bf16 bf16x8 __attribute__((ext_vector_type(8)));
typedef unsigned short u16x8 __attribute__((ext_vector_type(8)));
typedef float f32x4 __attribute__((ext_vector_type(4)));

#define M_ROWS 8232
#define SEQ 1029
#define NPREF 5
#define DIMN 1024
#define NH 16
#define HD 64

#define GP(p) ((__attribute__((address_space(1))) void*)(unsigned long long)(const void*)(p))
#define LP(p) ((__attribute__((address_space(3))) void*)(unsigned)(unsigned long long)(const void*)(p))

__device__ __forceinline__ u16 f2bf(float f) {
  unsigned u = __float_as_uint(f);
  u += 0x7fffu + ((u >> 16) & 1u);
  return (u16)(u >> 16);
}

__device__ __forceinline__ unsigned pk2bf(float lo, float hi) {
  unsigned ul = __float_as_uint(lo);
  unsigned uh = __float_as_uint(hi);
  ul += 0x7fffu + ((ul >> 16) & 1u);
  uh += 0x7fffu + ((uh >> 16) & 1u);
  return __builtin_amdgcn_perm(uh, ul, 0x07060302u);
}

// ---------------- x (fp32) -> bf16 ----------------
__global__ __launch_bounds__(256) void k_cvt_x(const float* __restrict__ x, u16* __restrict__ xb) {
  size_t i = ((size_t)blockIdx.x * 256 + threadIdx.x) * 4;
  float4 v = *reinterpret_cast<const float4*>(x + i);
  ushort4 o;
  o.x = f2bf(v.x); o.y = f2bf(v.y); o.z = f2bf(v.z); o.w = f2bf(v.w);
  *reinterpret_cast<ushort4*>(xb + i) = o;
}

// ---------------- W (fp32 [K][N]) -> WT (bf16 [N][K]) ----------------
__global__ __launch_bounds__(256) void k_wt(const float* __restrict__ W0, const float* __restrict__ W1,
                                            const float* __restrict__ W2, const float* __restrict__ W3,
                                            u16* __restrict__ T0, u16* __restrict__ T1,
                                            u16* __restrict__ T2, u16* __restrict__ T3) {
  const float* W; u16* T;
  switch (blockIdx.z) {
    case 0: W = W0; T = T0; break;
    case 1: W = W1; T = T1; break;
    case 2: W = W2; T = T2; break;
    default: W = W3; T = T3; break;
  }
  __shared__ float tile[32][33];
  int tx = threadIdx.x & 31, ty = threadIdx.x >> 5;
  int k0 = blockIdx.x * 32, n0 = blockIdx.y * 32;
#pragma unroll
  for (int j = 0; j < 4; ++j)
    tile[ty + j * 8][tx] = W[(size_t)(k0 + ty + j * 8) * DIMN + n0 + tx];
  __syncthreads();
#pragma unroll
  for (int j = 0; j < 4; ++j)
    T[(size_t)(n0 + ty + j * 8) * DIMN + k0 + tx] = f2bf(tile[tx][ty + j * 8]);
}

// ---------------- fused QKV projection GEMM ----------------
// grid: x = 24 (mode*8 + n-tile)  [fast-moving => all 24 share one A-tile in L2],
//       y = 65 m-tiles.
__global__ __launch_bounds__(256) void k_qkv(
    const u16* __restrict__ Xb,
    const u16* __restrict__ WqT, const u16* __restrict__ WkT, const u16* __restrict__ WvT,
    const float* __restrict__ bq, const float* __restrict__ bv,
    const float* __restrict__ rc, const float* __restrict__ rs,
    u16* __restrict__ Qg, u16* __restrict__ Kg, u16* __restrict__ Vg)
{
  int mode = blockIdx.x >> 3;
  int nt = blockIdx.x & 7;
  const u16* WT = (mode == 0) ? WqT : (mode == 1) ? WkT : WvT;
  u16* dst = (mode == 0) ? Qg : (mode == 1) ? Kg : Vg;
  int m0 = blockIdx.y * 128, n0 = nt * 128;

  __shared__ u16 Al[128 * 32];
  __shared__ u16 Bl[128 * 32];

  int t = threadIdx.x, lane = t & 63, wv = t >> 6;
  int fr = lane & 15, quad = lane >> 4;
  int wm = (wv >> 1) * 64, wn = (wv & 1) * 64;

  int srow = lane >> 2;
  int scol = (lane & 3) * 8;
  int ar0 = m0 + wv * 32 + srow; if (ar0 >= M_ROWS) ar0 = M_ROWS - 1;
  int ar1 = m0 + wv * 32 + 16 + srow; if (ar1 >= M_ROWS) ar1 = M_ROWS - 1;
  int br0 = n0 + wv * 32 + srow;
  int br1 = br0 + 16;
  const u16* agp0 = Xb + (size_t)ar0 * DIMN + scol;
  const u16* agp1 = Xb + (size_t)ar1 * DIMN + scol;
  const u16* bgp0 = WT + (size_t)br0 * DIMN + scol;
  const u16* bgp1 = WT + (size_t)br1 * DIMN + scol;
  u16* al0 = Al + wv * 1024;
  u16* al1 = Al + wv * 1024 + 512;
  u16* bl0 = Bl + wv * 1024;
  u16* bl1 = Bl + wv * 1024 + 512;

  f32x4 zero4 = {0.f, 0.f, 0.f, 0.f};
  f32x4 acc[4][4];
#pragma unroll
  for (int i = 0; i < 4; ++i)
#pragma unroll
    for (int j = 0; j < 4; ++j) acc[i][j] = zero4;

  for (int k0 = 0; k0 < DIMN; k0 += 32) {
    __syncthreads();
    __builtin_amdgcn_global_load_lds(GP(agp0 + k0), LP(al0), 16, 0, 0);
    __builtin_amdgcn_global_load_lds(GP(agp1 + k0), LP(al1), 16, 0, 0);
    __builtin_amdgcn_global_load_lds(GP(bgp0 + k0), LP(bl0), 16, 0, 0);
    __builtin_amdgcn_global_load_lds(GP(bgp1 + k0), LP(bl1), 16, 0, 0);
    __syncthreads();
    bf16x8 af[4], bfr[4];
#pragma unroll
    for (int i = 0; i < 4; ++i)
      af[i] = *reinterpret_cast<const bf16x8*>(&Al[(wm + i * 16 + fr) * 32 + quad * 8]);
#pragma unroll
    for (int j = 0; j < 4; ++j)
      bfr[j] = *reinterpret_cast<const bf16x8*>(&Bl[(wn + j * 16 + fr) * 32 + quad * 8]);
#pragma unroll
    for (int i = 0; i < 4; ++i)
#pragma unroll
      for (int j = 0; j < 4; ++j)
        acc[i][j] = __builtin_amdgcn_mfma_f32_16x16x32_bf16(af[i], bfr[j], acc[i][j], 0, 0, 0);
  }

  int h = (n0 + wn) >> 6;
#pragma unroll
  for (int i = 0; i < 4; ++i) {
    int rowbase = m0 + wm + i * 16 + quad * 4;
#pragma unroll
    for (int r = 0; r < 4; ++r) {
      int row = rowbase + r;
      if (row >= M_ROWS) continue;
      int b = row / SEQ;
      int s = row - b * SEQ;
#pragma unroll
      for (int j = 0; j < 4; ++j) {
        int d = j * 16 + fr;
        float v = acc[i][j][r];
        float outv;
        if (mode == 2) {
          outv = v + bv[n0 + wn + d];
        } else {
          float vb = v;
          int jp = j ^ 2;
          float pv = acc[i][jp][r];
          if (mode == 0) {
            vb += bq[n0 + wn + d];
            pv += bq[n0 + wn + (jp * 16 + fr)];
          }
          if (s >= NPREF) {
            int p = s - NPREF;
            float c = rc[p * HD + d];
            float sn = rs[p * HD + d];
            float rot = (d < 32) ? -pv : pv;
            outv = vb * c + rot * sn;
          } else {
            outv = vb;
          }
          if (mode == 0) outv *= 0.125f;
        }
        dst[((size_t)(b * NH + h) * SEQ + s) * HD + d] = f2bf(outv);
      }
    }
  }
}

// ---------------- flash attention, S^T layout, fixed-M softmax ----------------
__global__ __launch_bounds__(256) void k_attn(
    const u16* __restrict__ Qg, const u16* __restrict__ Kg, const u16* __restrict__ Vg,
    u16* __restrict__ AO)
{
  int q0 = blockIdx.x * 128;
  int bh = blockIdx.y;
  int b = bh >> 4, h = bh & 15;
  const size_t base = (size_t)bh * SEQ * HD;

  __shared__ u16 Ks[64 * 72];
  __shared__ u16 Vt[64 * 72];
  __shared__ u16 Ps[4][32 * 72];

  int t = threadIdx.x, lane = t & 63, wv = t >> 6;
  int fr = lane & 15, quad = lane >> 4;

  bf16x8 qf[2][2];
#pragma unroll
  for (int qt = 0; qt < 2; ++qt) {
#pragma unroll
    for (int st = 0; st < 2; ++st) {
      int row = q0 + wv * 32 + qt * 16 + fr;
      if (row >= SEQ) row = SEQ - 1;
      qf[qt][st] = *reinterpret_cast<const bf16x8*>(Qg + base + (size_t)row * HD + st * 32 + quad * 8);
    }
  }

  u16x8 one16 = {0x3F80, 0x3F80, 0x3F80, 0x3F80, 0x3F80, 0x3F80, 0x3F80, 0x3F80};
  bf16x8 vone = __builtin_bit_cast(bf16x8, one16);

  f32x4 zero4 = {0.f, 0.f, 0.f, 0.f};
  f32x4 o[2][5];
#pragma unroll
  for (int qt = 0; qt < 2; ++qt)
#pragma unroll
    for (int di = 0; di < 5; ++di) o[qt][di] = zero4;

  for (int kt = 0; kt < 17; ++kt) {
    int k0 = kt * 64;
    __syncthreads();
    {
      int i = t >> 2;
      int srow = k0 + i; if (srow >= SEQ) srow = SEQ - 1;
      const u16* src = Kg + base + (size_t)srow * HD;
      int c0 = (t & 3) * 16;
      *reinterpret_cast<uint4*>(&Ks[i * 72 + c0]) = *reinterpret_cast<const uint4*>(src + c0);
      *reinterpret_cast<uint4*>(&Ks[i * 72 + c0 + 8]) = *reinterpret_cast<const uint4*>(src + c0 + 8);
    }
    {
      int s0 = (t & 31) * 2;
      int doff = (t >> 5) * 8;
      int r0 = k0 + s0;     if (r0 >= SEQ) r0 = SEQ - 1;
      int r1 = k0 + s0 + 1; if (r1 >= SEQ) r1 = SEQ - 1;
      const u16* v0p = Vg + base + (size_t)r0 * HD + doff;
      const u16* v1p = Vg + base + (size_t)r1 * HD + doff;
      u16 v0[8], v1[8];
      *reinterpret_cast<uint4*>(v0) = *reinterpret_cast<const uint4*>(v0p);
      *reinterpret_cast<uint4*>(v1) = *reinterpret_cast<const uint4*>(v1p);
#pragma unroll
      for (int j = 0; j < 8; ++j) {
        unsigned pk = (unsigned)v0[j] | ((unsigned)v1[j] << 16);
        *reinterpret_cast<unsigned*>(&Vt[(doff + j) * 72 + s0]) = pk;
      }
    }
    __syncthreads();

    f32x4 sc[4][2];
#pragma unroll
    for (int mi = 0; mi < 4; ++mi)
#pragma unroll
      for (int qt = 0; qt < 2; ++qt) sc[mi][qt] = zero4;
#pragma unroll
    for (int st = 0; st < 2; ++st) {
#pragma unroll
      for (int mi = 0; mi < 4; ++mi) {
        bf16x8 kf = *reinterpret_cast<const bf16x8*>(&Ks[(mi * 16 + fr) * 72 + st * 32 + quad * 8]);
#pragma unroll
        for (int qt = 0; qt < 2; ++qt)
          sc[mi][qt] = __builtin_amdgcn_mfma_f32_16x16x32_bf16(kf, qf[qt][st], sc[mi][qt], 0, 0, 0);
      }
    }

    bool last = (kt == 16);
#pragma unroll
    for (int qt = 0; qt < 2; ++qt) {
#pragma unroll
      for (int mi = 0; mi < 4; ++mi) {
        float p0, p1, p2, p3;
        {
          float s0v = sc[mi][qt][0], s1v = sc[mi][qt][1], s2v = sc[mi][qt][2], s3v = sc[mi][qt][3];
          if (last) {
            int kc = mi * 16 + quad * 4;
            if (kc + 0 >= NPREF) s0v = -1e30f;
            if (kc + 1 >= NPREF) s1v = -1e30f;
            if (kc + 2 >= NPREF) s2v = -1e30f;
            if (kc + 3 >= NPREF) s3v = -1e30f;
          }
          p0 = __expf(s0v - 16.0f);
          p1 = __expf(s1v - 16.0f);
          p2 = __expf(s2v - 16.0f);
          p3 = __expf(s3v - 16.0f);
        }
        unsigned d0 = pk2bf(p0, p1);
        unsigned d1 = pk2bf(p2, p3);
        uint2 w; w.x = d0; w.y = d1;
        *reinterpret_cast<uint2*>(&Ps[wv][(qt * 16 + fr) * 72 + mi * 16 + quad * 4]) = w;
      }
    }

#pragma unroll
    for (int st = 0; st < 2; ++st) {
      bf16x8 pf[2];
#pragma unroll
      for (int qt = 0; qt < 2; ++qt)
        pf[qt] = *reinterpret_cast<const bf16x8*>(&Ps[wv][(qt * 16 + fr) * 72 + st * 32 + quad * 8]);
#pragma unroll
      for (int di = 0; di < 4; ++di) {
        bf16x8 vf = *reinterpret_cast<const bf16x8*>(&Vt[(di * 16 + fr) * 72 + st * 32 + quad * 8]);
#pragma unroll
        for (int qt = 0; qt < 2; ++qt)
          o[qt][di] = __builtin_amdgcn_mfma_f32_16x16x32_bf16(pf[qt], vf, o[qt][di], 0, 0, 0);
      }
#pragma unroll
      for (int qt = 0; qt < 2; ++qt)
        o[qt][4] = __builtin_amdgcn_mfma_f32_16x16x32_bf16(pf[qt], vone, o[qt][4], 0, 0, 0);
    }
  }

#pragma unroll
  for (int qt = 0; qt < 2; ++qt) {
#pragma unroll
    for (int r = 0; r < 4; ++r) {
      int srow = q0 + wv * 32 + qt * 16 + quad * 4 + r;
      if (srow >= SEQ) continue;
      float inv = 1.f / o[qt][4][r];
#pragma unroll
      for (int di = 0; di < 4; ++di) {
        float v = o[qt][di][r] * inv;
        AO[((size_t)b * SEQ + srow) * DIMN + h * HD + di * 16 + fr] = f2bf(v);
      }
    }
  }
}

// ---------------- output GEMM: Out = AO @ Wo + bo (fp32 out) ----------------
// grid: x = 8 n-tiles (fast => A-tile shared in L2), y = 65 m-tiles.
__global__ __launch_bounds__(256) void k_out(
    const u16* __restrict__ Ab, const u16* __restrict__ WoT,
    const float* __restrict__ bo, float* __restrict__ Out)
{
  int m0 = blockIdx.y * 128, n0 = blockIdx.x * 128;
  __shared__ u16 Al[128 * 32];
  __shared__ u16 Bl[128 * 32];

  int t = threadIdx.x, lane = t & 63, wv = t >> 6;
  int fr = lane & 15, quad = lane >> 4;
  int wm = (wv >> 1) * 64, wn = (wv & 1) * 64;

  int srow = lane >> 2;
  int scol = (lane & 3) * 8;
  int ar0 = m0 + wv * 32 + srow; if (ar0 >= M_ROWS) ar0 = M_ROWS - 1;
  int ar1 = m0 + wv * 32 + 16 + srow; if (ar1 >= M_ROWS) ar1 = M_ROWS - 1;
  int br0 = n0 + wv * 32 + srow;
  int br1 = br0 + 16;
  const u16* agp0 = Ab + (size_t)ar0 * DIMN + scol;
  const u16* agp1 = Ab + (size_t)ar1 * DIMN + scol;
  const u16* bgp0 = WoT + (size_t)br0 * DIMN + scol;
  const u16* bgp1 = WoT + (size_t)br1 * DIMN + scol;
  u16* al0 = Al + wv * 1024;
  u16* al1 = Al + wv * 1024 + 512;
  u16* bl0 = Bl + wv * 1024;
  u16* bl1 = Bl + wv * 1024 + 512;

  f32x4 zero4 = {0.f, 0.f, 0.f, 0.f};
  f32x4 acc[4][4];
#pragma unroll
  for (int i = 0; i < 4; ++i)
#pragma unroll
    for (int j = 0; j < 4; ++j) acc[i][j] = zero4;

  for (int k0 = 0; k0 < DIMN; k0 += 32) {
    __syncthreads();
    __builtin_amdgcn_global_load_lds(GP(agp0 + k0), LP(al0), 16, 0, 0);
    __builtin_amdgcn_global_load_lds(GP(agp1 + k0), LP(al1), 16, 0, 0);
    __builtin_amdgcn_global_load_lds(GP(bgp0 + k0), LP(bl0), 16, 0, 0);
    __builtin_amdgcn_global_load_lds(GP(bgp1 + k0), LP(bl1), 16, 0, 0);
    __syncthreads();
    bf16x8 af[4], bfr[4];
#pragma unroll
    for (int i = 0; i < 4; ++i)
      af[i] = *reinterpret_cast<const bf16x8*>(&Al[(wm + i * 16 + fr) * 32 + quad * 8]);
#pragma unroll
    for (int j = 0; j < 4; ++j)
      bfr[j] = *reinterpret_cast<const bf16x8*>(&Bl[(wn + j * 16 + fr) * 32 + quad * 8]);
#pragma unroll
    for (int i = 0; i < 4; ++i)
#pragma unroll
      for (int j = 0; j < 4; ++j)
        acc[i][j] = __builtin_amdgcn_mfma_f32_16x16x32_bf16(af[i], bfr[j], acc[i][j], 0, 0, 0);
  }

#pragma unroll
  for (int i = 0; i < 4; ++i) {
    int rowbase = m0 + wm + i * 16 + quad * 4;
#pragma unroll
    for (int r = 0; r < 4; ++r) {
      int row = rowbase + r;
      if (row >= M_ROWS) continue;
#pragma unroll
      for (int j = 0; j < 4; ++j) {
        int col = n0 + wn + j * 16 + fr;
        Out[(size_t)row * DIMN + col] = acc[i][j][r] + bo[col];
      }
    }
  }
}

extern "C" void kernel_launch(void* const* d_in, const int* in_sizes, int n_in,
                              void* d_out, int out_size, void* d_ws, size_t ws_size,
                              hipStream_t stream)
{
  const float* x  = (const float*)d_in[0];
  const float* rc = (const float*)d_in[1];
  const float* rs = (const float*)d_in[2];
  const float* Wq = (const float*)d_in[3];
  const float* bq = (const float*)d_in[4];
  const float* Wk = (const float*)d_in[5];
  const float* Wv = (const float*)d_in[6];
  const float* bv = (const float*)d_in[7];
  const float* Wo = (const float*)d_in[8];
  const float* bo = (const float*)d_in[9];
  float* Out = (float*)d_out;

  u16* p = (u16*)d_ws;
  u16* Xb  = p; p += (size_t)M_ROWS * DIMN;
  u16* WqT = p; p += (size_t)DIMN * DIMN;
  u16* WkT = p; p += (size_t)DIMN * DIMN;
  u16* WvT = p; p += (size_t)DIMN * DIMN;
  u16* WoT = p; p += (size_t)DIMN * DIMN;
  u16* Qg  = p; p += (size_t)M_ROWS * DIMN;
  u16* Kg  = p; p += (size_t)M_ROWS * DIMN;
  u16* Vg  = p; p += (size_t)M_ROWS * DIMN;
  u16* AO  = p; p += (size_t)M_ROWS * DIMN;

  k_cvt_x<<<M_ROWS, 256, 0, stream>>>(x, Xb);
  dim3 gt(32, 32, 4);
  k_wt<<<gt, 256, 0, stream>>>(Wq, Wk, Wv, Wo, WqT, WkT, WvT, WoT);
  dim3 g1(24, 65);
  k_qkv<<<g1, 256, 0, stream>>>(Xb, WqT, WkT, WvT, bq, bv, rc, rs, Qg, Kg, Vg);
  dim3 g2(9, 128);
  k_attn<<<g2, 256, 0, stream>>>(Qg, Kg, Vg, AO);
  dim3 g3(8, 65);
  k_out<<<g3, 256, 0, stream>>>(AO, WoT, bo, Out);
}

// Round 4
// 340.571 us; speedup vs baseline: 1.2779x; 1.0633x over previous
//
#include <hip/hip_runtime.h>

typedef unsigned short u16;
typedef __bf16 bf16x8 __attribute__((ext_vector_type(8)));
typedef unsigned short u16x8 __attribute__((ext_vector_type(8)));
typedef float f32x4 __attribute__((ext_vector_type(4)));

#define M_ROWS 8232
#define SEQ 1029
#define NPREF 5
#define DIMN 1024
#define NH 16
#define HD 64

#define GP(p) ((__attribute__((address_space(1))) void*)(unsigned long long)(const void*)(p))
#define LP(p) ((__attribute__((address_space(3))) void*)(unsigned)(unsigned long long)(const void*)(p))

// raw barriers: never drain vmcnt(0) (keep async loads in flight across barrier)
#define BAR_VM4  asm volatile("s_waitcnt vmcnt(4)\ns_barrier" ::: "memory")
#define BAR_VM0  asm volatile("s_waitcnt vmcnt(0)\ns_barrier" ::: "memory")
#define BAR_LGKM asm volatile("s_waitcnt lgkmcnt(0)\ns_barrier" ::: "memory")

__device__ __forceinline__ u16 f2bf(float f) {
  unsigned u = __float_as_uint(f);
  u += 0x7fffu + ((u >> 16) & 1u);
  return (u16)(u >> 16);
}

__device__ __forceinline__ unsigned pk2bf(float lo, float hi) {
  unsigned ul = __float_as_uint(lo);
  unsigned uh = __float_as_uint(hi);
  ul += 0x7fffu + ((ul >> 16) & 1u);
  uh += 0x7fffu + ((uh >> 16) & 1u);
  return __builtin_amdgcn_perm(uh, ul, 0x07060302u);
}

// ---------------- x (fp32) -> bf16 ----------------
__global__ __launch_bounds__(256) void k_cvt_x(const float* __restrict__ x, u16* __restrict__ xb) {
  size_t i = ((size_t)blockIdx.x * 256 + threadIdx.x) * 4;
  float4 v = *reinterpret_cast<const float4*>(x + i);
  ushort4 o;
  o.x = f2bf(v.x); o.y = f2bf(v.y); o.z = f2bf(v.z); o.w = f2bf(v.w);
  *reinterpret_cast<ushort4*>(xb + i) = o;
}

// ---------------- W (fp32 [K][N]) -> WT (bf16 [N][K]) ----------------
__global__ __launch_bounds__(256) void k_wt(const float* __restrict__ W0, const float* __restrict__ W1,
                                            const float* __restrict__ W2, const float* __restrict__ W3,
                                            u16* __restrict__ T0, u16* __restrict__ T1,
                                            u16* __restrict__ T2, u16* __restrict__ T3) {
  const float* W; u16* T;
  switch (blockIdx.z) {
    case 0: W = W0; T = T0; break;
    case 1: W = W1; T = T1; break;
    case 2: W = W2; T = T2; break;
    default: W = W3; T = T3; break;
  }
  __shared__ float tile[32][33];
  int tx = threadIdx.x & 31, ty = threadIdx.x >> 5;
  int k0 = blockIdx.x * 32, n0 = blockIdx.y * 32;
#pragma unroll
  for (int j = 0; j < 4; ++j)
    tile[ty + j * 8][tx] = W[(size_t)(k0 + ty + j * 8) * DIMN + n0 + tx];
  __syncthreads();
#pragma unroll
  for (int j = 0; j < 4; ++j)
    T[(size_t)(n0 + ty + j * 8) * DIMN + k0 + tx] = f2bf(tile[tx][ty + j * 8]);
}

// ---------------- fused QKV projection GEMM, async dbuf pipeline ----------------
// 1D grid 1728: bid%8 locks all 24 (mode,nt) sharers of an m-tile onto one XCD.
__global__ __launch_bounds__(256) void k_qkv(
    const u16* __restrict__ Xb,
    const u16* __restrict__ WqT, const u16* __restrict__ WkT, const u16* __restrict__ WvT,
    const float* __restrict__ bq, const float* __restrict__ bv,
    const float* __restrict__ rc, const float* __restrict__ rs,
    u16* __restrict__ Qg, u16* __restrict__ Kg, u16* __restrict__ Vg)
{
  int bid = blockIdx.x;
  int rxcd = bid & 7, tt = bid >> 3;
  int mq = tt / 24, j24 = tt - mq * 24;
  int mt = mq * 8 + rxcd;
  if (mt >= 65) return;
  int mode = j24 >> 3, nt = j24 & 7;
  const u16* WT = (mode == 0) ? WqT : (mode == 1) ? WkT : WvT;
  u16* dst = (mode == 0) ? Qg : (mode == 1) ? Kg : Vg;
  int m0 = mt * 128, n0 = nt * 128;

  __shared__ u16 Al[2][128 * 32];
  __shared__ u16 Bl[2][128 * 32];

  int t = threadIdx.x, lane = t & 63, wv = t >> 6;
  int fr = lane & 15, quad = lane >> 4;
  int wm = (wv >> 1) * 64, wn = (wv & 1) * 64;

  int srow = lane >> 2;
  int scol = (lane & 3) * 8;
  int ar0 = m0 + wv * 32 + srow; if (ar0 >= M_ROWS) ar0 = M_ROWS - 1;
  int ar1 = m0 + wv * 32 + 16 + srow; if (ar1 >= M_ROWS) ar1 = M_ROWS - 1;
  int br0 = n0 + wv * 32 + srow;
  int br1 = br0 + 16;
  const u16* agp0 = Xb + (size_t)ar0 * DIMN + scol;
  const u16* agp1 = Xb + (size_t)ar1 * DIMN + scol;
  const u16* bgp0 = WT + (size_t)br0 * DIMN + scol;
  const u16* bgp1 = WT + (size_t)br1 * DIMN + scol;

#define QKV_ISSUE(koff, bb) do { \
    __builtin_amdgcn_global_load_lds(GP(agp0 + (koff)), LP(&Al[bb][wv * 1024]), 16, 0, 0); \
    __builtin_amdgcn_global_load_lds(GP(agp1 + (koff)), LP(&Al[bb][wv * 1024 + 512]), 16, 0, 0); \
    __builtin_amdgcn_global_load_lds(GP(bgp0 + (koff)), LP(&Bl[bb][wv * 1024]), 16, 0, 0); \
    __builtin_amdgcn_global_load_lds(GP(bgp1 + (koff)), LP(&Bl[bb][wv * 1024 + 512]), 16, 0, 0); \
  } while (0)

  f32x4 zero4 = {0.f, 0.f, 0.f, 0.f};
  f32x4 acc[4][4];
#pragma unroll
  for (int i = 0; i < 4; ++i)
#pragma unroll
    for (int j = 0; j < 4; ++j) acc[i][j] = zero4;

  QKV_ISSUE(0, 0);
  QKV_ISSUE(32, 1);
  for (int kk = 0; kk < 32; ++kk) {
    int bb = kk & 1;
    if (kk < 31) { BAR_VM4; } else { BAR_VM0; }
    bf16x8 af[4], bfr[4];
#pragma unroll
    for (int i = 0; i < 4; ++i)
      af[i] = *reinterpret_cast<const bf16x8*>(&Al[bb][(wm + i * 16 + fr) * 32 + quad * 8]);
#pragma unroll
    for (int j = 0; j < 4; ++j)
      bfr[j] = *reinterpret_cast<const bf16x8*>(&Bl[bb][(wn + j * 16 + fr) * 32 + quad * 8]);
#pragma unroll
    for (int i = 0; i < 4; ++i)
#pragma unroll
      for (int j = 0; j < 4; ++j)
        acc[i][j] = __builtin_amdgcn_mfma_f32_16x16x32_bf16(af[i], bfr[j], acc[i][j], 0, 0, 0);
    if (kk < 30) {
      BAR_LGKM;
      QKV_ISSUE((kk + 2) * 32, bb);
    }
  }

  int h = (n0 + wn) >> 6;
#pragma unroll
  for (int i = 0; i < 4; ++i) {
    int rowbase = m0 + wm + i * 16 + quad * 4;
#pragma unroll
    for (int r = 0; r < 4; ++r) {
      int row = rowbase + r;
      if (row >= M_ROWS) continue;
      int b = row / SEQ;
      int s = row - b * SEQ;
#pragma unroll
      for (int j = 0; j < 4; ++j) {
        int d = j * 16 + fr;
        float v = acc[i][j][r];
        float outv;
        if (mode == 2) {
          outv = v + bv[n0 + wn + d];
        } else {
          float vb = v;
          int jp = j ^ 2;
          float pv = acc[i][jp][r];
          if (mode == 0) {
            vb += bq[n0 + wn + d];
            pv += bq[n0 + wn + (jp * 16 + fr)];
          }
          if (s >= NPREF) {
            int p = s - NPREF;
            float c = rc[p * HD + d];
            float sn = rs[p * HD + d];
            float rot = (d < 32) ? -pv : pv;
            outv = vb * c + rot * sn;
          } else {
            outv = vb;
          }
          if (mode == 0) outv *= 0.125f;
        }
        dst[((size_t)(b * NH + h) * SEQ + s) * HD + d] = f2bf(outv);
      }
    }
  }
}

// ---------------- flash attention, S^T layout, reg-prefetch K/V ----------------
// grid (x=128 bh, y=9 qt): bh%8 constant across a bh's 9 q-tiles -> one XCD's L2.
__global__ __launch_bounds__(256) void k_attn(
    const u16* __restrict__ Qg, const u16* __restrict__ Kg, const u16* __restrict__ Vg,
    u16* __restrict__ AO)
{
  int bh = blockIdx.x;
  int q0 = blockIdx.y * 128;
  int b = bh >> 4, h = bh & 15;
  const size_t base = (size_t)bh * SEQ * HD;

  __shared__ u16 Ks[64 * 72];
  __shared__ u16 Vt[64 * 72];
  __shared__ u16 Ps[4][32 * 72];

  int t = threadIdx.x, lane = t & 63, wv = t >> 6;
  int fr = lane & 15, quad = lane >> 4;

  // staging geometry
  int ki = t >> 2;            // K row 0..63
  int kc0 = (t & 3) * 16;     // K col elem {0,16,32,48}
  int vs0 = (t & 31) * 2;     // V col pair
  int vdo = (t >> 5) * 8;     // V d-offset

  bf16x8 qf[2][2];
#pragma unroll
  for (int qt = 0; qt < 2; ++qt) {
#pragma unroll
    for (int st = 0; st < 2; ++st) {
      int row = q0 + wv * 32 + qt * 16 + fr;
      if (row >= SEQ) row = SEQ - 1;
      qf[qt][st] = *reinterpret_cast<const bf16x8*>(Qg + base + (size_t)row * HD + st * 32 + quad * 8);
    }
  }

  u16x8 one16 = {0x3F80, 0x3F80, 0x3F80, 0x3F80, 0x3F80, 0x3F80, 0x3F80, 0x3F80};
  bf16x8 vone = __builtin_bit_cast(bf16x8, one16);

  f32x4 zero4 = {0.f, 0.f, 0.f, 0.f};
  f32x4 o[2][5];
#pragma unroll
  for (int qt = 0; qt < 2; ++qt)
#pragma unroll
    for (int di = 0; di < 5; ++di) o[qt][di] = zero4;

  // prologue: load tile 0 into regs
  uint4 krA0, krA1, vrA0, vrA1;
  {
    int kr = ki; if (kr >= SEQ) kr = SEQ - 1;
    const u16* ksrc = Kg + base + (size_t)kr * HD;
    krA0 = *reinterpret_cast<const uint4*>(ksrc + kc0);
    krA1 = *reinterpret_cast<const uint4*>(ksrc + kc0 + 8);
    int r0 = vs0; if (r0 >= SEQ) r0 = SEQ - 1;
    int r1 = vs0 + 1; if (r1 >= SEQ) r1 = SEQ - 1;
    vrA0 = *reinterpret_cast<const uint4*>(Vg + base + (size_t)r0 * HD + vdo);
    vrA1 = *reinterpret_cast<const uint4*>(Vg + base + (size_t)r1 * HD + vdo);
  }

  for (int kt = 0; kt < 17; ++kt) {
    int k0 = kt * 64;
    BAR_LGKM;  // all waves done reading previous K/V tile
    // ds_write current tile from regs
    *reinterpret_cast<uint4*>(&Ks[ki * 72 + kc0]) = krA0;
    *reinterpret_cast<uint4*>(&Ks[ki * 72 + kc0 + 8]) = krA1;
    {
      u16 v0[8], v1[8];
      *reinterpret_cast<uint4*>(v0) = vrA0;
      *reinterpret_cast<uint4*>(v1) = vrA1;
#pragma unroll
      for (int j = 0; j < 8; ++j) {
        unsigned pk = (unsigned)v0[j] | ((unsigned)v1[j] << 16);
        *reinterpret_cast<unsigned*>(&Vt[(vdo + j) * 72 + vs0]) = pk;
      }
    }
    // prefetch next tile into regs (stays in flight across the compute phase)
    if (kt < 16) {
      int kn = k0 + 64;
      int kr = kn + ki; if (kr >= SEQ) kr = SEQ - 1;
      const u16* ksrc = Kg + base + (size_t)kr * HD;
      krA0 = *reinterpret_cast<const uint4*>(ksrc + kc0);
      krA1 = *reinterpret_cast<const uint4*>(ksrc + kc0 + 8);
      int r0 = kn + vs0; if (r0 >= SEQ) r0 = SEQ - 1;
      int r1 = kn + vs0 + 1; if (r1 >= SEQ) r1 = SEQ - 1;
      vrA0 = *reinterpret_cast<const uint4*>(Vg + base + (size_t)r0 * HD + vdo);
      vrA1 = *reinterpret_cast<const uint4*>(Vg + base + (size_t)r1 * HD + vdo);
    }
    BAR_LGKM;  // staged tile visible to all waves

    f32x4 sc[4][2];
#pragma unroll
    for (int mi = 0; mi < 4; ++mi)
#pragma unroll
      for (int qt = 0; qt < 2; ++qt) sc[mi][qt] = zero4;
#pragma unroll
    for (int st = 0; st < 2; ++st) {
#pragma unroll
      for (int mi = 0; mi < 4; ++mi) {
        bf16x8 kf = *reinterpret_cast<const bf16x8*>(&Ks[(mi * 16 + fr) * 72 + st * 32 + quad * 8]);
#pragma unroll
        for (int qt = 0; qt < 2; ++qt)
          sc[mi][qt] = __builtin_amdgcn_mfma_f32_16x16x32_bf16(kf, qf[qt][st], sc[mi][qt], 0, 0, 0);
      }
    }

    bool last = (kt == 16);
#pragma unroll
    for (int qt = 0; qt < 2; ++qt) {
#pragma unroll
      for (int mi = 0; mi < 4; ++mi) {
        float p0, p1, p2, p3;
        {
          float s0v = sc[mi][qt][0], s1v = sc[mi][qt][1], s2v = sc[mi][qt][2], s3v = sc[mi][qt][3];
          if (last) {
            int kc = mi * 16 + quad * 4;
            if (kc + 0 >= NPREF) s0v = -1e30f;
            if (kc + 1 >= NPREF) s1v = -1e30f;
            if (kc + 2 >= NPREF) s2v = -1e30f;
            if (kc + 3 >= NPREF) s3v = -1e30f;
          }
          p0 = __expf(s0v - 16.0f);
          p1 = __expf(s1v - 16.0f);
          p2 = __expf(s2v - 16.0f);
          p3 = __expf(s3v - 16.0f);
        }
        unsigned d0 = pk2bf(p0, p1);
        unsigned d1 = pk2bf(p2, p3);
        uint2 w; w.x = d0; w.y = d1;
        *reinterpret_cast<uint2*>(&Ps[wv][(qt * 16 + fr) * 72 + mi * 16 + quad * 4]) = w;
      }
    }

#pragma unroll
    for (int st = 0; st < 2; ++st) {
      bf16x8 pf[2];
#pragma unroll
      for (int qt = 0; qt < 2; ++qt)
        pf[qt] = *reinterpret_cast<const bf16x8*>(&Ps[wv][(qt * 16 + fr) * 72 + st * 32 + quad * 8]);
#pragma unroll
      for (int di = 0; di < 4; ++di) {
        bf16x8 vf = *reinterpret_cast<const bf16x8*>(&Vt[(di * 16 + fr) * 72 + st * 32 + quad * 8]);
#pragma unroll
        for (int qt = 0; qt < 2; ++qt)
          o[qt][di] = __builtin_amdgcn_mfma_f32_16x16x32_bf16(pf[qt], vf, o[qt][di], 0, 0, 0);
      }
#pragma unroll
      for (int qt = 0; qt < 2; ++qt)
        o[qt][4] = __builtin_amdgcn_mfma_f32_16x16x32_bf16(pf[qt], vone, o[qt][4], 0, 0, 0);
    }
  }

#pragma unroll
  for (int qt = 0; qt < 2; ++qt) {
#pragma unroll
    for (int r = 0; r < 4; ++r) {
      int srow = q0 + wv * 32 + qt * 16 + quad * 4 + r;
      if (srow >= SEQ) continue;
      float inv = 1.f / o[qt][4][r];
#pragma unroll
      for (int di = 0; di < 4; ++di) {
        float v = o[qt][di][r] * inv;
        AO[((size_t)b * SEQ + srow) * DIMN + h * HD + di * 16 + fr] = f2bf(v);
      }
    }
  }
}

// ---------------- output GEMM, async dbuf pipeline ----------------
// 1D grid 576: bid%8 locks all 8 n-tiles of an m-tile onto one XCD.
__global__ __launch_bounds__(256) void k_out(
    const u16* __restrict__ Ab, const u16* __restrict__ WoT,
    const float* __restrict__ bo, float* __restrict__ Out)
{
  int bid = blockIdx.x;
  int rxcd = bid & 7, tt = bid >> 3;
  int mq = tt >> 3, nt = tt & 7;
  int mt = mq * 8 + rxcd;
  if (mt >= 65) return;
  int m0 = mt * 128, n0 = nt * 128;

  __shared__ u16 Al[2][128 * 32];
  __shared__ u16 Bl[2][128 * 32];

  int t = threadIdx.x, lane = t & 63, wv = t >> 6;
  int fr = lane & 15, quad = lane >> 4;
  int wm = (wv >> 1) * 64, wn = (wv & 1) * 64;

  int srow = lane >> 2;
  int scol = (lane & 3) * 8;
  int ar0 = m0 + wv * 32 + srow; if (ar0 >= M_ROWS) ar0 = M_ROWS - 1;
  int ar1 = m0 + wv * 32 + 16 + srow; if (ar1 >= M_ROWS) ar1 = M_ROWS - 1;
  int br0 = n0 + wv * 32 + srow;
  int br1 = br0 + 16;
  const u16* agp0 = Ab + (size_t)ar0 * DIMN + scol;
  const u16* agp1 = Ab + (size_t)ar1 * DIMN + scol;
  const u16* bgp0 = WoT + (size_t)br0 * DIMN + scol;
  const u16* bgp1 = WoT + (size_t)br1 * DIMN + scol;

#define OUT_ISSUE(koff, bb) do { \
    __builtin_amdgcn_global_load_lds(GP(agp0 + (koff)), LP(&Al[bb][wv * 1024]), 16, 0, 0); \
    __builtin_amdgcn_global_load_lds(GP(agp1 + (koff)), LP(&Al[bb][wv * 1024 + 512]), 16, 0, 0); \
    __builtin_amdgcn_global_load_lds(GP(bgp0 + (koff)), LP(&Bl[bb][wv * 1024]), 16, 0, 0); \
    __builtin_amdgcn_global_load_lds(GP(bgp1 + (koff)), LP(&Bl[bb][wv * 1024 + 512]), 16, 0, 0); \
  } while (0)

  f32x4 zero4 = {0.f, 0.f, 0.f, 0.f};
  f32x4 acc[4][4];
#pragma unroll
  for (int i = 0; i < 4; ++i)
#pragma unroll
    for (int j = 0; j < 4; ++j) acc[i][j] = zero4;

  OUT_ISSUE(0, 0);
  OUT_ISSUE(32, 1);
  for (int kk = 0; kk < 32; ++kk) {
    int bb = kk & 1;
    if (kk < 31) { BAR_VM4; } else { BAR_VM0; }
    bf16x8 af[4], bfr[4];
#pragma unroll
    for (int i = 0; i < 4; ++i)
      af[i] = *reinterpret_cast<const bf16x8*>(&Al[bb][(wm + i * 16 + fr) * 32 + quad * 8]);
#pragma unroll
    for (int j = 0; j < 4; ++j)
      bfr[j] = *reinterpret_cast<const bf16x8*>(&Bl[bb][(wn + j * 16 + fr) * 32 + quad * 8]);
#pragma unroll
    for (int i = 0; i < 4; ++i)
#pragma unroll
      for (int j = 0; j < 4; ++j)
        acc[i][j] = __builtin_amdgcn_mfma_f32_16x16x32_bf16(af[i], bfr[j], acc[i][j], 0, 0, 0);
    if (kk < 30) {
      BAR_LGKM;
      OUT_ISSUE((kk + 2) * 32, bb);
    }
  }

#pragma unroll
  for (int i = 0; i < 4; ++i) {
    int rowbase = m0 + wm + i * 16 + quad * 4;
#pragma unroll
    for (int r = 0; r < 4; ++r) {
      int row = rowbase + r;
      if (row >= M_ROWS) continue;
#pragma unroll
      for (int j = 0; j < 4; ++j) {
        int col = n0 + wn + j * 16 + fr;
        Out[(size_t)row * DIMN + col] = acc[i][j][r] + bo[col];
      }
    }
  }
}

extern "C" void kernel_launch(void* const* d_in, const int* in_sizes, int n_in,
                              void* d_out, int out_size, void* d_ws, size_t ws_size,
                              hipStream_t stream)
{
  const float* x  = (const float*)d_in[0];
  const float* rc = (const float*)d_in[1];
  const float* rs = (const float*)d_in[2];
  const float* Wq = (const float*)d_in[3];
  const float* bq = (const float*)d_in[4];
  const float* Wk = (const float*)d_in[5];
  const float* Wv = (const float*)d_in[6];
  const float* bv = (const float*)d_in[7];
  const float* Wo = (const float*)d_in[8];
  const float* bo = (const float*)d_in[9];
  float* Out = (float*)d_out;

  u16* p = (u16*)d_ws;
  u16* Xb  = p; p += (size_t)M_ROWS * DIMN;
  u16* WqT = p; p += (size_t)DIMN * DIMN;
  u16* WkT = p; p += (size_t)DIMN * DIMN;
  u16* WvT = p; p += (size_t)DIMN * DIMN;
  u16* WoT = p; p += (size_t)DIMN * DIMN;
  u16* Qg  = p; p += (size_t)M_ROWS * DIMN;
  u16* Kg  = p; p += (size_t)M_ROWS * DIMN;
  u16* Vg  = p; p += (size_t)M_ROWS * DIMN;
  u16* AO  = p; p += (size_t)M_ROWS * DIMN;

  k_cvt_x<<<M_ROWS, 256, 0, stream>>>(x, Xb);
  dim3 gt(32, 32, 4);
  k_wt<<<gt, 256, 0, stream>>>(Wq, Wk, Wv, Wo, WqT, WkT, WvT, WoT);
  k_qkv<<<1728, 256, 0, stream>>>(Xb, WqT, WkT, WvT, bq, bv, rc, rs, Qg, Kg, Vg);
  dim3 g2(128, 9);
  k_attn<<<g2, 256, 0, stream>>>(Qg, Kg, Vg, AO);
  k_out<<<576, 256, 0, stream>>>(AO, WoT, bo, Out);
}